// Round 1
// baseline (1380.889 us; speedup 1.0000x reference)
//
#include <hip/hip_runtime.h>
#include <hip/hip_bf16.h>
#include <cstdint>

#define NFEAT 384
#define DESK 768
#define THIRD 128

__device__ __forceinline__ float leaky(float x) { return x > 0.f ? x : 0.01f * x; }

// ---------------- big tiled fp32 GEMM, 128x128 tile, 256 thr, 8x8 micro ----
// EPI 0: C = leaky(A@B + bias)
// EPI 1: C = leaky(A@B + s[row]*u[col] + bias[col])
template <int EPI>
__global__ __launch_bounds__(256) void gemm_epi(
    const float* __restrict__ A, const float* __restrict__ B,
    float* __restrict__ C, int M, int lda, int ldb, int ldc,
    int K, const float* __restrict__ bias, const float* __restrict__ uvec,
    const float* __restrict__ svec) {
  __shared__ float As[16][132];
  __shared__ float Bs[16][128];
  const int tid = threadIdx.x;
  const int m_base = blockIdx.x * 128;
  const int n_base = blockIdx.y * 128;
  float acc[8][8] = {};
  const int arow = tid >> 2;   // 0..63
  const int akq = tid & 3;     // 0..3
  const int brow = tid >> 5;   // 0..7
  const int bc4 = tid & 31;    // 0..31
  const int m0 = (tid >> 4) * 8;
  const int n0 = (tid & 15) * 8;

  for (int kk = 0; kk < K; kk += 16) {
#pragma unroll
    for (int h = 0; h < 2; h++) {
      int r = arow + h * 64;
      int gr = m_base + r;
      float4 av = make_float4(0.f, 0.f, 0.f, 0.f);
      if (gr < M) av = *(const float4*)&A[(size_t)gr * lda + kk + akq * 4];
      As[akq * 4 + 0][r] = av.x;
      As[akq * 4 + 1][r] = av.y;
      As[akq * 4 + 2][r] = av.z;
      As[akq * 4 + 3][r] = av.w;
    }
#pragma unroll
    for (int h = 0; h < 2; h++) {
      int kr = brow + h * 8;
      *(float4*)&Bs[kr][bc4 * 4] =
          *(const float4*)&B[(size_t)(kk + kr) * ldb + n_base + bc4 * 4];
    }
    __syncthreads();
#pragma unroll
    for (int k = 0; k < 16; k++) {
      float4 a0 = *(const float4*)&As[k][m0];
      float4 a1 = *(const float4*)&As[k][m0 + 4];
      float4 b0 = *(const float4*)&Bs[k][n0];
      float4 b1 = *(const float4*)&Bs[k][n0 + 4];
      float a[8] = {a0.x, a0.y, a0.z, a0.w, a1.x, a1.y, a1.z, a1.w};
      float b[8] = {b0.x, b0.y, b0.z, b0.w, b1.x, b1.y, b1.z, b1.w};
#pragma unroll
      for (int i = 0; i < 8; i++)
#pragma unroll
        for (int j = 0; j < 8; j++) acc[i][j] = fmaf(a[i], b[j], acc[i][j]);
    }
    __syncthreads();
  }
#pragma unroll
  for (int i = 0; i < 8; i++) {
    int row = m_base + m0 + i;
    if (row >= M) break;
    float sv = (EPI == 1) ? svec[row] : 0.f;
#pragma unroll
    for (int j = 0; j < 8; j++) {
      int col = n_base + n0 + j;
      float val = acc[i][j];
      if (EPI == 0) {
        val = leaky(val + bias[col]);
      } else {
        val = leaky(val + sv * uvec[col] + bias[col]);
      }
      C[(size_t)row * ldc + col] = val;
    }
  }
}

// ---------------- small 384x384x384 GEMM (plain C = A@B) --------------------
__global__ __launch_bounds__(256) void gemm384(const float* __restrict__ A,
                                               const float* __restrict__ B,
                                               float* __restrict__ C) {
  __shared__ float As[16][68];
  __shared__ float Bs[16][64];
  const int tid = threadIdx.x;
  const int mb = blockIdx.x * 64;
  const int nb = blockIdx.y * 64;
  float acc[4][4] = {};
  const int arow = tid >> 2, akq = tid & 3;
  const int brow = tid >> 4, bc4 = tid & 15;
  const int m0 = (tid >> 4) * 4, n0 = (tid & 15) * 4;
  for (int kk = 0; kk < 384; kk += 16) {
    float4 av = *(const float4*)&A[(mb + arow) * 384 + kk + akq * 4];
    As[akq * 4 + 0][arow] = av.x;
    As[akq * 4 + 1][arow] = av.y;
    As[akq * 4 + 2][arow] = av.z;
    As[akq * 4 + 3][arow] = av.w;
    *(float4*)&Bs[brow][bc4 * 4] =
        *(const float4*)&B[(kk + brow) * 384 + nb + bc4 * 4];
    __syncthreads();
#pragma unroll
    for (int k = 0; k < 16; k++) {
      float4 a4 = *(const float4*)&As[k][m0];
      float4 b4 = *(const float4*)&Bs[k][n0];
      float a[4] = {a4.x, a4.y, a4.z, a4.w};
      float b[4] = {b4.x, b4.y, b4.z, b4.w};
#pragma unroll
      for (int i = 0; i < 4; i++)
#pragma unroll
        for (int j = 0; j < 4; j++) acc[i][j] = fmaf(a[i], b[j], acc[i][j]);
    }
    __syncthreads();
  }
#pragma unroll
  for (int i = 0; i < 4; i++)
#pragma unroll
    for (int j = 0; j < 4; j++)
      C[(mb + m0 + i) * 384 + nb + n0 + j] = acc[i][j];
}

// u[j] = sum_k T1[k][j]*b_g1[k] ; v[j] = sum_k W_o1[k][j]*b_g2[k] + b_o1[j]
__global__ void uv_kernel(const float* __restrict__ T1,
                          const float* __restrict__ W_o1,
                          const float* __restrict__ b_g1,
                          const float* __restrict__ b_g2,
                          const float* __restrict__ b_o1, float* __restrict__ u,
                          float* __restrict__ v) {
  int j = blockIdx.x * blockDim.x + threadIdx.x;
  if (j < 384) {
    float su = 0.f, sv = 0.f;
    for (int k = 0; k < 384; k++) {
      su = fmaf(T1[k * 384 + j], b_g1[k], su);
      sv = fmaf(W_o1[k * 384 + j], b_g2[k], sv);
    }
    u[j] = su;
    v[j] = sv + b_o1[j];
  }
}

// num/cat -> x0 columns 128..383
__global__ __launch_bounds__(256) void numcat_kernel(
    const float* __restrict__ num, const float* __restrict__ cat,
    const float* __restrict__ Wn, const float* __restrict__ bn,
    const float* __restrict__ Wc, const float* __restrict__ bc,
    float* __restrict__ x0) {
  int i = blockIdx.x;
  int c = threadIdx.x;
  float val;
  if (c < 128) {
    val = bn[c];
    val = fmaf(num[i * 4 + 0], Wn[0 * 128 + c], val);
    val = fmaf(num[i * 4 + 1], Wn[1 * 128 + c], val);
    val = fmaf(num[i * 4 + 2], Wn[2 * 128 + c], val);
    val = fmaf(num[i * 4 + 3], Wn[3 * 128 + c], val);
  } else {
    int cc = c - 128;
    val = bc[cc];
    val = fmaf(cat[i * 3 + 0], Wc[0 * 128 + cc], val);
    val = fmaf(cat[i * 3 + 1], Wc[1 * 128 + cc], val);
    val = fmaf(cat[i * 3 + 2], Wc[2 * 128 + cc], val);
  }
  x0[(size_t)i * NFEAT + 128 + c] = leaky(val);
}

// ---------------- graph prep -----------------------------------------------
__global__ void count_kernel(const int* __restrict__ dst, int* __restrict__ deg,
                             int E) {
  int e = blockIdx.x * blockDim.x + threadIdx.x;
  if (e < E) atomicAdd(&deg[dst[e]], 1);
}

__global__ void scan_reduce(const int* __restrict__ deg,
                            int* __restrict__ partial, int N) {
  __shared__ int sm[512];
  int i = blockIdx.x * 512 + threadIdx.x;
  sm[threadIdx.x] = (i < N) ? deg[i] : 0;
  __syncthreads();
  for (int off = 256; off; off >>= 1) {
    if (threadIdx.x < off) sm[threadIdx.x] += sm[threadIdx.x + off];
    __syncthreads();
  }
  if (threadIdx.x == 0) partial[blockIdx.x] = sm[0];
}

__global__ void scan_top(int* partial, int nb) {
  if (threadIdx.x == 0 && blockIdx.x == 0) {
    int run = 0;
    for (int b = 0; b < nb; b++) {
      int t = partial[b];
      partial[b] = run;
      run += t;
    }
  }
}

__global__ void scan_down(const int* __restrict__ deg,
                          const int* __restrict__ partial,
                          int* __restrict__ offsets, int* __restrict__ cursor,
                          int N, int E) {
  __shared__ int sm[512];
  int t = threadIdx.x;
  int i = blockIdx.x * 512 + t;
  int val = (i < N) ? deg[i] : 0;
  sm[t] = val;
  __syncthreads();
  for (int off = 1; off < 512; off <<= 1) {
    int add = (t >= off) ? sm[t - off] : 0;
    __syncthreads();
    sm[t] += add;
    __syncthreads();
  }
  if (i < N) {
    int ex = partial[blockIdx.x] + sm[t] - val;
    offsets[i] = ex;
    cursor[i] = ex;
  }
  if (i == 0) offsets[N] = E;
}

__global__ void dinv_kernel(const int* __restrict__ deg,
                            float* __restrict__ dinv, int N) {
  int i = blockIdx.x * blockDim.x + threadIdx.x;
  if (i < N) dinv[i] = 1.0f / sqrtf((float)deg[i] + 1.0f);
}

__global__ void fill_kernel(const int* __restrict__ src,
                            const int* __restrict__ dst,
                            int* __restrict__ cursor,
                            int* __restrict__ csr_src,
                            float* __restrict__ csr_w,
                            const float* __restrict__ dinv, int E) {
  int e = blockIdx.x * blockDim.x + threadIdx.x;
  if (e < E) {
    int s = src[e], d = dst[e];
    int slot = atomicAdd(&cursor[d], 1);
    csr_src[slot] = s;
    csr_w[slot] = dinv[s] * dinv[d];
  }
}

// ---------------- aggregation: xout = Ahat @ xin ----------------------------
template <int WRITE_S>
__global__ __launch_bounds__(384) void agg_kernel(
    const float* __restrict__ xin, float* __restrict__ xout,
    const int* __restrict__ offsets, const int* __restrict__ csr_src,
    const float* __restrict__ csr_w, const float* __restrict__ dinv,
    float* __restrict__ sout) {
  int i = blockIdx.x;
  int f = threadIdx.x;
  int beg = offsets[i], end = offsets[i + 1];
  float di = dinv[i];
  float acc = di * di * xin[(size_t)i * NFEAT + f];
  float wsum = di * di;
  __shared__ int ssrc[384];
  __shared__ float sw[384];
  for (int j0 = beg; j0 < end; j0 += 384) {
    int cnt = min(384, end - j0);
    if (f < cnt) {
      ssrc[f] = csr_src[j0 + f];
      sw[f] = csr_w[j0 + f];
    }
    __syncthreads();
    for (int j = 0; j < cnt; j++) {
      float w = sw[j];
      acc = fmaf(w, xin[(size_t)ssrc[j] * NFEAT + f], acc);
      if (WRITE_S) wsum += w;
    }
    __syncthreads();
  }
  xout[(size_t)i * NFEAT + f] = acc;
  if (WRITE_S && f == 0) sout[i] = wsum;
}

// ---------------- final tiny GEMM: out = x4 @ W_o2 + b_o2 -------------------
__global__ __launch_bounds__(256) void out_kernel(
    const float* __restrict__ x4, const float* __restrict__ W_o2,
    const float* __restrict__ b_o2, float* __restrict__ out, int N) {
  int wid = threadIdx.x >> 6;
  int lane = threadIdx.x & 63;
  int i = blockIdx.x * 4 + wid;
  if (i >= N) return;
  float p0 = 0.f, p1 = 0.f;
  for (int f = lane; f < NFEAT; f += 64) {
    float xv = x4[(size_t)i * NFEAT + f];
    p0 = fmaf(xv, W_o2[f * 2 + 0], p0);
    p1 = fmaf(xv, W_o2[f * 2 + 1], p1);
  }
  for (int off = 32; off; off >>= 1) {
    p0 += __shfl_down(p0, off, 64);
    p1 += __shfl_down(p1, off, 64);
  }
  if (lane == 0) {
    out[i * 2 + 0] = p0 + b_o2[0];
    out[i * 2 + 1] = p1 + b_o2[1];
  }
}

extern "C" void kernel_launch(void* const* d_in, const int* in_sizes, int n_in,
                              void* d_out, int out_size, void* d_ws,
                              size_t ws_size, hipStream_t stream) {
  const float* des = (const float*)d_in[0];
  // d_in[1] = tweet : unused by the reference
  const float* num_prop = (const float*)d_in[2];
  const float* cat_prop = (const float*)d_in[3];
  const int* edge = (const int*)d_in[4];
  const float* W_des = (const float*)d_in[5];
  const float* b_des = (const float*)d_in[6];
  const float* W_num = (const float*)d_in[7];
  const float* b_num = (const float*)d_in[8];
  const float* W_cat = (const float*)d_in[9];
  const float* b_cat = (const float*)d_in[10];
  const float* W_in = (const float*)d_in[11];
  const float* b_in = (const float*)d_in[12];
  const float* W_g1 = (const float*)d_in[13];
  const float* b_g1 = (const float*)d_in[14];
  const float* W_g2 = (const float*)d_in[15];
  const float* b_g2 = (const float*)d_in[16];
  const float* W_o1 = (const float*)d_in[17];
  const float* b_o1 = (const float*)d_in[18];
  const float* W_o2 = (const float*)d_in[19];
  const float* b_o2 = (const float*)d_in[20];
  float* out = (float*)d_out;

  const int N = in_sizes[0] / DESK;   // 50000
  const int E = in_sizes[4] / 2;      // 800000
  const int* esrc = edge;
  const int* edst = edge + E;

  // workspace layout
  char* ws = (char*)d_ws;
  size_t off = 0;
  auto alloc = [&](size_t n) {
    off = (off + 255) & ~(size_t)255;
    size_t o = off;
    off += n;
    return o;
  };
  float* xb0 = (float*)(ws + alloc((size_t)N * NFEAT * 4));
  float* xb1 = (float*)(ws + alloc((size_t)N * NFEAT * 4));
  int* deg = (int*)(ws + alloc((size_t)N * 4));
  int* offsets = (int*)(ws + alloc((size_t)(N + 1) * 4));
  int* cursor = (int*)(ws + alloc((size_t)N * 4));
  int* partial = (int*)(ws + alloc(1024 * 4));
  float* dinv = (float*)(ws + alloc((size_t)N * 4));
  float* svec = (float*)(ws + alloc((size_t)N * 4));
  int* csr_src = (int*)(ws + alloc((size_t)E * 4));
  float* csr_w = (float*)(ws + alloc((size_t)E * 4));
  float* T1 = (float*)(ws + alloc(384 * 384 * 4));
  float* Mmat = (float*)(ws + alloc(384 * 384 * 4));
  float* uvec = (float*)(ws + alloc(384 * 4));
  float* vvec = (float*)(ws + alloc(384 * 4));
  (void)ws_size;
  (void)n_in;
  (void)out_size;

  hipMemsetAsync(deg, 0, (size_t)N * 4, stream);

  // small precomputes: T1 = W_g2 @ W_o1 ; Mmat = W_g1 @ T1 ; u, v
  dim3 g6(6, 6);
  gemm384<<<g6, 256, 0, stream>>>(W_g2, W_o1, T1);
  gemm384<<<g6, 256, 0, stream>>>(W_g1, T1, Mmat);
  uv_kernel<<<2, 256, 0, stream>>>(T1, W_o1, b_g1, b_g2, b_o1, uvec, vvec);

  const int MT = (N + 127) / 128;  // 391
  // x0 cols 0..127 = leaky(des @ W_des + b_des)
  gemm_epi<0><<<dim3(MT, 1), 256, 0, stream>>>(des, W_des, xb0, N, DESK, THIRD,
                                               NFEAT, DESK, b_des, nullptr,
                                               nullptr);
  // x0 cols 128..383
  numcat_kernel<<<N, 256, 0, stream>>>(num_prop, cat_prop, W_num, b_num, W_cat,
                                       b_cat, xb0);
  // x1 = leaky(x0 @ W_in + b_in)
  gemm_epi<0><<<dim3(MT, 3), 256, 0, stream>>>(xb0, W_in, xb1, N, NFEAT, NFEAT,
                                               NFEAT, NFEAT, b_in, nullptr,
                                               nullptr);

  // graph prep
  const int EB = (E + 255) / 256;
  count_kernel<<<EB, 256, 0, stream>>>(edst, deg, E);
  const int NB = (N + 511) / 512;
  scan_reduce<<<NB, 512, 0, stream>>>(deg, partial, N);
  scan_top<<<1, 64, 0, stream>>>(partial, NB);
  scan_down<<<NB, 512, 0, stream>>>(deg, partial, offsets, cursor, N, E);
  dinv_kernel<<<(N + 255) / 256, 256, 0, stream>>>(deg, dinv, N);
  fill_kernel<<<EB, 256, 0, stream>>>(esrc, edst, cursor, csr_src, csr_w, dinv,
                                      E);

  // z = Ahat @ x1 (also produce s = Ahat @ 1) ; z2 = Ahat @ z
  agg_kernel<1><<<N, 384, 0, stream>>>(xb1, xb0, offsets, csr_src, csr_w, dinv,
                                       svec);
  agg_kernel<0><<<N, 384, 0, stream>>>(xb0, xb1, offsets, csr_src, csr_w, dinv,
                                       nullptr);

  // x4 = leaky(z2 @ Mmat + s*u + v)
  gemm_epi<1><<<dim3(MT, 3), 256, 0, stream>>>(xb1, Mmat, xb0, N, NFEAT, NFEAT,
                                               NFEAT, NFEAT, vvec, uvec, svec);
  // out = x4 @ W_o2 + b_o2
  out_kernel<<<(N + 3) / 4, 256, 0, stream>>>(xb0, W_o2, b_o2, out, N);
}

// Round 2
// 1342.851 us; speedup vs baseline: 1.0283x; 1.0283x over previous
//
#include <hip/hip_runtime.h>
#include <hip/hip_bf16.h>
#include <cstdint>

#define NFEAT 384
#define DESK 768
#define THIRD 128

__device__ __forceinline__ float leaky(float x) { return x > 0.f ? x : 0.01f * x; }

// ---------------- big tiled fp32 GEMM, 128x128 tile, 256 thr, 8x8 micro ----
// EPI 0: C = leaky(A@B + bias)
// EPI 2: C = A@B (plain)
template <int EPI>
__global__ __launch_bounds__(256) void gemm_epi(
    const float* __restrict__ A, const float* __restrict__ B,
    float* __restrict__ C, int M, int lda, int ldb, int ldc,
    int K, const float* __restrict__ bias) {
  __shared__ float As[16][132];
  __shared__ float Bs[16][128];
  const int tid = threadIdx.x;
  const int m_base = blockIdx.x * 128;
  const int n_base = blockIdx.y * 128;
  float acc[8][8] = {};
  const int arow = tid >> 2;   // 0..63
  const int akq = tid & 3;     // 0..3
  const int brow = tid >> 5;   // 0..7
  const int bc4 = tid & 31;    // 0..31
  const int m0 = (tid >> 4) * 8;
  const int nA = (tid & 15) * 4;  // cols nA..nA+3 and 64+nA..64+nA+3

  for (int kk = 0; kk < K; kk += 16) {
#pragma unroll
    for (int h = 0; h < 2; h++) {
      int r = arow + h * 64;
      int gr = m_base + r;
      float4 av = make_float4(0.f, 0.f, 0.f, 0.f);
      if (gr < M) av = *(const float4*)&A[(size_t)gr * lda + kk + akq * 4];
      As[akq * 4 + 0][r] = av.x;
      As[akq * 4 + 1][r] = av.y;
      As[akq * 4 + 2][r] = av.z;
      As[akq * 4 + 3][r] = av.w;
    }
#pragma unroll
    for (int h = 0; h < 2; h++) {
      int kr = brow + h * 8;
      *(float4*)&Bs[kr][bc4 * 4] =
          *(const float4*)&B[(size_t)(kk + kr) * ldb + n_base + bc4 * 4];
    }
    __syncthreads();
#pragma unroll
    for (int k = 0; k < 16; k++) {
      float4 a0 = *(const float4*)&As[k][m0];
      float4 a1 = *(const float4*)&As[k][m0 + 4];
      float4 b0 = *(const float4*)&Bs[k][nA];
      float4 b1 = *(const float4*)&Bs[k][nA + 64];
      float a[8] = {a0.x, a0.y, a0.z, a0.w, a1.x, a1.y, a1.z, a1.w};
      float b[8] = {b0.x, b0.y, b0.z, b0.w, b1.x, b1.y, b1.z, b1.w};
#pragma unroll
      for (int i = 0; i < 8; i++)
#pragma unroll
        for (int j = 0; j < 8; j++) acc[i][j] = fmaf(a[i], b[j], acc[i][j]);
    }
    __syncthreads();
  }
  float4 bia0 = make_float4(0.f, 0.f, 0.f, 0.f);
  float4 bia1 = make_float4(0.f, 0.f, 0.f, 0.f);
  if (EPI == 0) {
    bia0 = *(const float4*)&bias[n_base + nA];
    bia1 = *(const float4*)&bias[n_base + 64 + nA];
  }
#pragma unroll
  for (int i = 0; i < 8; i++) {
    int row = m_base + m0 + i;
    if (row >= M) break;
    float4 r0, r1;
    if (EPI == 0) {
      r0.x = leaky(acc[i][0] + bia0.x);
      r0.y = leaky(acc[i][1] + bia0.y);
      r0.z = leaky(acc[i][2] + bia0.z);
      r0.w = leaky(acc[i][3] + bia0.w);
      r1.x = leaky(acc[i][4] + bia1.x);
      r1.y = leaky(acc[i][5] + bia1.y);
      r1.z = leaky(acc[i][6] + bia1.z);
      r1.w = leaky(acc[i][7] + bia1.w);
    } else {
      r0 = make_float4(acc[i][0], acc[i][1], acc[i][2], acc[i][3]);
      r1 = make_float4(acc[i][4], acc[i][5], acc[i][6], acc[i][7]);
    }
    *(float4*)&C[(size_t)row * ldc + n_base + nA] = r0;
    *(float4*)&C[(size_t)row * ldc + n_base + 64 + nA] = r1;
  }
}

// ---------------- small 384x384x384 GEMM (plain C = A@B) --------------------
__global__ __launch_bounds__(256) void gemm384(const float* __restrict__ A,
                                               const float* __restrict__ B,
                                               float* __restrict__ C) {
  __shared__ float As[16][68];
  __shared__ float Bs[16][64];
  const int tid = threadIdx.x;
  const int mb = blockIdx.x * 64;
  const int nb = blockIdx.y * 64;
  float acc[4][4] = {};
  const int arow = tid >> 2, akq = tid & 3;
  const int brow = tid >> 4, bc4 = tid & 15;
  const int m0 = (tid >> 4) * 4, n0 = (tid & 15) * 4;
  for (int kk = 0; kk < 384; kk += 16) {
    float4 av = *(const float4*)&A[(mb + arow) * 384 + kk + akq * 4];
    As[akq * 4 + 0][arow] = av.x;
    As[akq * 4 + 1][arow] = av.y;
    As[akq * 4 + 2][arow] = av.z;
    As[akq * 4 + 3][arow] = av.w;
    *(float4*)&Bs[brow][bc4 * 4] =
        *(const float4*)&B[(kk + brow) * 384 + nb + bc4 * 4];
    __syncthreads();
#pragma unroll
    for (int k = 0; k < 16; k++) {
      float4 a4 = *(const float4*)&As[k][m0];
      float4 b4 = *(const float4*)&Bs[k][n0];
      float a[4] = {a4.x, a4.y, a4.z, a4.w};
      float b[4] = {b4.x, b4.y, b4.z, b4.w};
#pragma unroll
      for (int i = 0; i < 4; i++)
#pragma unroll
        for (int j = 0; j < 4; j++) acc[i][j] = fmaf(a[i], b[j], acc[i][j]);
    }
    __syncthreads();
  }
#pragma unroll
  for (int i = 0; i < 4; i++)
#pragma unroll
    for (int j = 0; j < 4; j++)
      C[(mb + m0 + i) * 384 + nb + n0 + j] = acc[i][j];
}

// u[j] = sum_k T1[k][j]*b_g1[k] ; v[j] = sum_k W_o1[k][j]*b_g2[k] + b_o1[j]
__global__ void uv_kernel(const float* __restrict__ T1,
                          const float* __restrict__ W_o1,
                          const float* __restrict__ b_g1,
                          const float* __restrict__ b_g2,
                          const float* __restrict__ b_o1, float* __restrict__ u,
                          float* __restrict__ v) {
  int j = blockIdx.x * blockDim.x + threadIdx.x;
  if (j < 384) {
    float su = 0.f, sv = 0.f;
    for (int k = 0; k < 384; k++) {
      su = fmaf(T1[k * 384 + j], b_g1[k], su);
      sv = fmaf(W_o1[k * 384 + j], b_g2[k], sv);
    }
    u[j] = su;
    v[j] = sv + b_o1[j];
  }
}

// num/cat -> x0 columns 128..383
__global__ __launch_bounds__(256) void numcat_kernel(
    const float* __restrict__ num, const float* __restrict__ cat,
    const float* __restrict__ Wn, const float* __restrict__ bn,
    const float* __restrict__ Wc, const float* __restrict__ bc,
    float* __restrict__ x0) {
  int i = blockIdx.x;
  int c = threadIdx.x;
  float val;
  if (c < 128) {
    val = bn[c];
    val = fmaf(num[i * 4 + 0], Wn[0 * 128 + c], val);
    val = fmaf(num[i * 4 + 1], Wn[1 * 128 + c], val);
    val = fmaf(num[i * 4 + 2], Wn[2 * 128 + c], val);
    val = fmaf(num[i * 4 + 3], Wn[3 * 128 + c], val);
  } else {
    int cc = c - 128;
    val = bc[cc];
    val = fmaf(cat[i * 3 + 0], Wc[0 * 128 + cc], val);
    val = fmaf(cat[i * 3 + 1], Wc[1 * 128 + cc], val);
    val = fmaf(cat[i * 3 + 2], Wc[2 * 128 + cc], val);
  }
  x0[(size_t)i * NFEAT + 128 + c] = leaky(val);
}

// ---------------- graph prep -----------------------------------------------
__global__ void count_kernel(const int* __restrict__ dst, int* __restrict__ deg,
                             int E) {
  int e = blockIdx.x * blockDim.x + threadIdx.x;
  if (e < E) atomicAdd(&deg[dst[e]], 1);
}

__global__ void scan_reduce(const int* __restrict__ deg,
                            int* __restrict__ partial, int N) {
  __shared__ int sm[512];
  int i = blockIdx.x * 512 + threadIdx.x;
  sm[threadIdx.x] = (i < N) ? deg[i] : 0;
  __syncthreads();
  for (int off = 256; off; off >>= 1) {
    if (threadIdx.x < off) sm[threadIdx.x] += sm[threadIdx.x + off];
    __syncthreads();
  }
  if (threadIdx.x == 0) partial[blockIdx.x] = sm[0];
}

__global__ void scan_top(int* partial, int nb) {
  if (threadIdx.x == 0 && blockIdx.x == 0) {
    int run = 0;
    for (int b = 0; b < nb; b++) {
      int t = partial[b];
      partial[b] = run;
      run += t;
    }
  }
}

__global__ void scan_down(const int* __restrict__ deg,
                          const int* __restrict__ partial,
                          int* __restrict__ offsets, int* __restrict__ cursor,
                          int N, int E) {
  __shared__ int sm[512];
  int t = threadIdx.x;
  int i = blockIdx.x * 512 + t;
  int val = (i < N) ? deg[i] : 0;
  sm[t] = val;
  __syncthreads();
  for (int off = 1; off < 512; off <<= 1) {
    int add = (t >= off) ? sm[t - off] : 0;
    __syncthreads();
    sm[t] += add;
    __syncthreads();
  }
  if (i < N) {
    int ex = partial[blockIdx.x] + sm[t] - val;
    offsets[i] = ex;
    cursor[i] = ex;
  }
  if (i == 0) offsets[N] = E;
}

__global__ void dinv_kernel(const int* __restrict__ deg,
                            float* __restrict__ dinv, int N) {
  int i = blockIdx.x * blockDim.x + threadIdx.x;
  if (i < N) dinv[i] = 1.0f / sqrtf((float)deg[i] + 1.0f);
}

// csr_off stores src*NFEAT (premultiplied row offset)
__global__ void fill_kernel(const int* __restrict__ src,
                            const int* __restrict__ dst,
                            int* __restrict__ cursor,
                            int* __restrict__ csr_off,
                            float* __restrict__ csr_w,
                            const float* __restrict__ dinv, int E) {
  int e = blockIdx.x * blockDim.x + threadIdx.x;
  if (e < E) {
    int s = src[e], d = dst[e];
    int slot = atomicAdd(&cursor[d], 1);
    csr_off[slot] = s * NFEAT;
    csr_w[slot] = dinv[s] * dinv[d];
  }
}

// ---------------- aggregation: xout = Ahat @ xin ----------------------------
// WRITE_S: also write s_i = (Ahat @ 1)_i
// FINAL:   epilogue leaky(acc + s_i*u[f] + v[f]) -> dot with W_o2 -> out[i,0:2]
template <int WRITE_S, int FINAL>
__global__ __launch_bounds__(384) void agg_kernel(
    const float* __restrict__ xin, float* __restrict__ xout,
    const int* __restrict__ offsets, const int* __restrict__ csr_off,
    const float* __restrict__ csr_w, const float* __restrict__ dinv,
    float* __restrict__ sout, const float* __restrict__ svec,
    const float* __restrict__ uvec, const float* __restrict__ vvec,
    const float* __restrict__ W_o2, const float* __restrict__ b_o2,
    float* __restrict__ out) {
  int i = blockIdx.x;
  int f = threadIdx.x;
  int beg = offsets[i], end = offsets[i + 1];
  float di = dinv[i];
  float acc0 = di * di * xin[(size_t)i * NFEAT + f];
  float acc1 = 0.f;
  float wsum = di * di;
  __shared__ int ssrc[384];
  __shared__ float sw[384];
  for (int j0 = beg; j0 < end; j0 += 384) {
    int cnt = min(384, end - j0);
    if (f < cnt) {
      ssrc[f] = csr_off[j0 + f];
      sw[f] = csr_w[j0 + f];
    }
    __syncthreads();
    int j = 0;
    for (; j + 4 <= cnt; j += 4) {
      int o0 = ssrc[j], o1 = ssrc[j + 1], o2 = ssrc[j + 2], o3 = ssrc[j + 3];
      float w0 = sw[j], w1 = sw[j + 1], w2 = sw[j + 2], w3 = sw[j + 3];
      float v0 = xin[o0 + f];
      float v1 = xin[o1 + f];
      float v2 = xin[o2 + f];
      float v3 = xin[o3 + f];
      acc0 = fmaf(w0, v0, acc0);
      acc1 = fmaf(w1, v1, acc1);
      acc0 = fmaf(w2, v2, acc0);
      acc1 = fmaf(w3, v3, acc1);
      if (WRITE_S) wsum += (w0 + w1) + (w2 + w3);
    }
    for (; j < cnt; j++) {
      float w = sw[j];
      acc0 = fmaf(w, xin[ssrc[j] + f], acc0);
      if (WRITE_S) wsum += w;
    }
    __syncthreads();
  }
  float acc = acc0 + acc1;
  if (!FINAL) {
    xout[(size_t)i * NFEAT + f] = acc;
    if (WRITE_S && f == 0) sout[i] = wsum;
  } else {
    float val = leaky(acc + svec[i] * uvec[f] + vvec[f]);
    float c0 = val * W_o2[f * 2 + 0];
    float c1 = val * W_o2[f * 2 + 1];
#pragma unroll
    for (int off2 = 32; off2; off2 >>= 1) {
      c0 += __shfl_down(c0, off2, 64);
      c1 += __shfl_down(c1, off2, 64);
    }
    __shared__ float red[6][2];
    int wid = f >> 6, lane = f & 63;
    if (lane == 0) {
      red[wid][0] = c0;
      red[wid][1] = c1;
    }
    __syncthreads();
    if (f == 0) {
      float s0 = red[0][0] + red[1][0] + red[2][0] + red[3][0] + red[4][0] +
                 red[5][0];
      float s1 = red[0][1] + red[1][1] + red[2][1] + red[3][1] + red[4][1] +
                 red[5][1];
      out[i * 2 + 0] = s0 + b_o2[0];
      out[i * 2 + 1] = s1 + b_o2[1];
    }
  }
}

extern "C" void kernel_launch(void* const* d_in, const int* in_sizes, int n_in,
                              void* d_out, int out_size, void* d_ws,
                              size_t ws_size, hipStream_t stream) {
  const float* des = (const float*)d_in[0];
  // d_in[1] = tweet : unused by the reference
  const float* num_prop = (const float*)d_in[2];
  const float* cat_prop = (const float*)d_in[3];
  const int* edge = (const int*)d_in[4];
  const float* W_des = (const float*)d_in[5];
  const float* b_des = (const float*)d_in[6];
  const float* W_num = (const float*)d_in[7];
  const float* b_num = (const float*)d_in[8];
  const float* W_cat = (const float*)d_in[9];
  const float* b_cat = (const float*)d_in[10];
  const float* W_in = (const float*)d_in[11];
  const float* b_in = (const float*)d_in[12];
  const float* W_g1 = (const float*)d_in[13];
  const float* b_g1 = (const float*)d_in[14];
  const float* W_g2 = (const float*)d_in[15];
  const float* b_g2 = (const float*)d_in[16];
  const float* W_o1 = (const float*)d_in[17];
  const float* b_o1 = (const float*)d_in[18];
  const float* W_o2 = (const float*)d_in[19];
  const float* b_o2 = (const float*)d_in[20];
  float* out = (float*)d_out;

  const int N = in_sizes[0] / DESK;   // 50000
  const int E = in_sizes[4] / 2;      // 800000
  const int* esrc = edge;
  const int* edst = edge + E;

  // workspace layout
  char* ws = (char*)d_ws;
  size_t off = 0;
  auto alloc = [&](size_t n) {
    off = (off + 255) & ~(size_t)255;
    size_t o = off;
    off += n;
    return o;
  };
  float* xb0 = (float*)(ws + alloc((size_t)N * NFEAT * 4));
  float* xb1 = (float*)(ws + alloc((size_t)N * NFEAT * 4));
  int* deg = (int*)(ws + alloc((size_t)N * 4));
  int* offsets = (int*)(ws + alloc((size_t)(N + 1) * 4));
  int* cursor = (int*)(ws + alloc((size_t)N * 4));
  int* partial = (int*)(ws + alloc(1024 * 4));
  float* dinv = (float*)(ws + alloc((size_t)N * 4));
  float* svec = (float*)(ws + alloc((size_t)N * 4));
  int* csr_off = (int*)(ws + alloc((size_t)E * 4));
  float* csr_w = (float*)(ws + alloc((size_t)E * 4));
  float* T1 = (float*)(ws + alloc(384 * 384 * 4));
  float* Mmat = (float*)(ws + alloc(384 * 384 * 4));
  float* uvec = (float*)(ws + alloc(384 * 4));
  float* vvec = (float*)(ws + alloc(384 * 4));
  (void)ws_size;
  (void)n_in;
  (void)out_size;

  hipMemsetAsync(deg, 0, (size_t)N * 4, stream);

  // small precomputes: T1 = W_g2 @ W_o1 ; Mmat = W_g1 @ T1 ; u, v
  dim3 g6(6, 6);
  gemm384<<<g6, 256, 0, stream>>>(W_g2, W_o1, T1);
  gemm384<<<g6, 256, 0, stream>>>(W_g1, T1, Mmat);
  uv_kernel<<<2, 256, 0, stream>>>(T1, W_o1, b_g1, b_g2, b_o1, uvec, vvec);

  const int MT = (N + 127) / 128;  // 391
  // x0 cols 0..127 = leaky(des @ W_des + b_des)
  gemm_epi<0><<<dim3(MT, 1), 256, 0, stream>>>(des, W_des, xb0, N, DESK, THIRD,
                                               NFEAT, DESK, b_des);
  // x0 cols 128..383
  numcat_kernel<<<N, 256, 0, stream>>>(num_prop, cat_prop, W_num, b_num, W_cat,
                                       b_cat, xb0);
  // x1 = leaky(x0 @ W_in + b_in)  (xb0 -> xb1)
  gemm_epi<0><<<dim3(MT, 3), 256, 0, stream>>>(xb0, W_in, xb1, N, NFEAT, NFEAT,
                                               NFEAT, NFEAT, b_in);
  // y = x1 @ Mmat  (xb1 -> xb0)   [M commutes past the aggregations]
  gemm_epi<2><<<dim3(MT, 3), 256, 0, stream>>>(xb1, Mmat, xb0, N, NFEAT, NFEAT,
                                               NFEAT, NFEAT, nullptr);

  // graph prep
  const int EB = (E + 255) / 256;
  count_kernel<<<EB, 256, 0, stream>>>(edst, deg, E);
  const int NB = (N + 511) / 512;
  scan_reduce<<<NB, 512, 0, stream>>>(deg, partial, N);
  scan_top<<<1, 64, 0, stream>>>(partial, NB);
  scan_down<<<NB, 512, 0, stream>>>(deg, partial, offsets, cursor, N, E);
  dinv_kernel<<<(N + 255) / 256, 256, 0, stream>>>(deg, dinv, N);
  fill_kernel<<<EB, 256, 0, stream>>>(esrc, edst, cursor, csr_off, csr_w, dinv,
                                      E);

  // w1 = Ahat @ y (also s = Ahat @ 1) ; then fused final:
  // out = (leaky(Ahat @ w1 + s*u + v)) @ W_o2 + b_o2
  agg_kernel<1, 0><<<N, 384, 0, stream>>>(xb0, xb1, offsets, csr_off, csr_w,
                                          dinv, svec, nullptr, nullptr, nullptr,
                                          nullptr, nullptr, nullptr);
  agg_kernel<0, 1><<<N, 384, 0, stream>>>(xb1, nullptr, offsets, csr_off, csr_w,
                                          dinv, nullptr, svec, uvec, vvec, W_o2,
                                          b_o2, out);
}

// Round 3
// 1093.738 us; speedup vs baseline: 1.2625x; 1.2278x over previous
//
#include <hip/hip_runtime.h>
#include <hip/hip_bf16.h>
#include <cstdint>

#define NFEAT 384
#define DESK 768
#define THIRD 128

typedef __bf16 bf16x8 __attribute__((ext_vector_type(8)));
typedef unsigned short u16x8 __attribute__((ext_vector_type(8)));
typedef unsigned short u16x4 __attribute__((ext_vector_type(4)));
typedef float f32x16 __attribute__((ext_vector_type(16)));

__device__ __forceinline__ float leaky(float x) { return x > 0.f ? x : 0.01f * x; }

__device__ __forceinline__ unsigned short bfhi(float x) {
  unsigned int u = __float_as_uint(x);
  u += 0x7fffu + ((u >> 16) & 1u);
  return (unsigned short)(u >> 16);
}
__device__ __forceinline__ float bf2f(unsigned short h) {
  return __uint_as_float(((unsigned int)h) << 16);
}
__device__ __forceinline__ void bsplit(float x, unsigned short& h,
                                       unsigned short& l) {
  h = bfhi(x);
  l = bfhi(x - bf2f(h));
}

#define MFMA(a, b, c) __builtin_amdgcn_mfma_f32_32x32x16_bf16(a, b, c, 0, 0, 0)

// ---------------- split-bf16 MFMA GEMM -------------------------------------
// C[M x N] = A[M x K] @ B[K x N], N-tile=128 per blockIdx.y, BM=128, BK=32.
// A: either fp32 (AFP32=1, split in staging) or bf16 hi/lo planes.
// B: pre-split transposed planes BT[N][K] (hi/lo bf16).
// EPI 0: leaky(x+bias) -> write bf16 hi/lo planes Chi/Clo
// EPI 1: plain fp32 write to Cf
template <int AFP32, int EPI>
__global__ __launch_bounds__(256, 2) void mfma_gemm(
    const float* __restrict__ Af, const unsigned short* __restrict__ Ahi,
    const unsigned short* __restrict__ Alo,
    const unsigned short* __restrict__ BThi,
    const unsigned short* __restrict__ BTlo, float* __restrict__ Cf,
    unsigned short* __restrict__ Chi, unsigned short* __restrict__ Clo,
    const float* __restrict__ bias, int M, int K, int ldc) {
  __shared__ unsigned short AhiL[4 * 128 * 8];
  __shared__ unsigned short AloL[4 * 128 * 8];
  __shared__ unsigned short BhiL[4 * 128 * 8];
  __shared__ unsigned short BloL[4 * 128 * 8];
  const int tid = threadIdx.x;
  const int lane = tid & 63;
  const int w = tid >> 6;
  const int wm = (w >> 1) * 64, wn = (w & 1) * 64;
  const int lm = lane & 31, lk = lane >> 5;
  const int m_base = blockIdx.x * 128, n_base = blockIdx.y * 128;
  f32x16 a00 = {0.f, 0.f, 0.f, 0.f, 0.f, 0.f, 0.f, 0.f,
                0.f, 0.f, 0.f, 0.f, 0.f, 0.f, 0.f, 0.f};
  f32x16 a01 = a00, a10 = a00, a11 = a00;

  for (int kt = 0; kt < K; kt += 32) {
    if (AFP32) {
#pragma unroll
      for (int it = 0; it < 4; it++) {
        int r = (tid >> 3) + it * 32;
        int q = tid & 7;
        int gr = m_base + r;
        float4 av = make_float4(0.f, 0.f, 0.f, 0.f);
        if (gr < M) av = *(const float4*)&Af[(size_t)gr * K + kt + q * 4];
        unsigned short h0, h1, h2, h3, l0, l1, l2, l3;
        bsplit(av.x, h0, l0);
        bsplit(av.y, h1, l1);
        bsplit(av.z, h2, l2);
        bsplit(av.w, h3, l3);
        int base = ((q >> 1) * 128 + r) * 8 + (q & 1) * 4;
        u16x4 th;
        th.x = h0; th.y = h1; th.z = h2; th.w = h3;
        u16x4 tl;
        tl.x = l0; tl.y = l1; tl.z = l2; tl.w = l3;
        *(u16x4*)&AhiL[base] = th;
        *(u16x4*)&AloL[base] = tl;
      }
    } else {
#pragma unroll
      for (int it = 0; it < 2; it++) {
        int r = (tid >> 2) + it * 64;
        int kb = tid & 3;
        int gr = m_base + r;
        u16x8 vh = {0, 0, 0, 0, 0, 0, 0, 0};
        u16x8 vl = {0, 0, 0, 0, 0, 0, 0, 0};
        if (gr < M) {
          vh = *(const u16x8*)&Ahi[(size_t)gr * K + kt + kb * 8];
          vl = *(const u16x8*)&Alo[(size_t)gr * K + kt + kb * 8];
        }
        *(u16x8*)&AhiL[(kb * 128 + r) * 8] = vh;
        *(u16x8*)&AloL[(kb * 128 + r) * 8] = vl;
      }
    }
#pragma unroll
    for (int it = 0; it < 2; it++) {
      int n = (tid >> 2) + it * 64;
      int kb = tid & 3;
      *(u16x8*)&BhiL[(kb * 128 + n) * 8] =
          *(const u16x8*)&BThi[(size_t)(n_base + n) * K + kt + kb * 8];
      *(u16x8*)&BloL[(kb * 128 + n) * 8] =
          *(const u16x8*)&BTlo[(size_t)(n_base + n) * K + kt + kb * 8];
    }
    __syncthreads();
#pragma unroll
    for (int ks = 0; ks < 2; ks++) {
      int kb = 2 * ks + lk;
      bf16x8 ah0 = __builtin_bit_cast(
          bf16x8, *(const u16x8*)&AhiL[(kb * 128 + wm + lm) * 8]);
      bf16x8 ah1 = __builtin_bit_cast(
          bf16x8, *(const u16x8*)&AhiL[(kb * 128 + wm + 32 + lm) * 8]);
      bf16x8 al0 = __builtin_bit_cast(
          bf16x8, *(const u16x8*)&AloL[(kb * 128 + wm + lm) * 8]);
      bf16x8 al1 = __builtin_bit_cast(
          bf16x8, *(const u16x8*)&AloL[(kb * 128 + wm + 32 + lm) * 8]);
      bf16x8 bh0 = __builtin_bit_cast(
          bf16x8, *(const u16x8*)&BhiL[(kb * 128 + wn + lm) * 8]);
      bf16x8 bh1 = __builtin_bit_cast(
          bf16x8, *(const u16x8*)&BhiL[(kb * 128 + wn + 32 + lm) * 8]);
      bf16x8 bl0 = __builtin_bit_cast(
          bf16x8, *(const u16x8*)&BloL[(kb * 128 + wn + lm) * 8]);
      bf16x8 bl1 = __builtin_bit_cast(
          bf16x8, *(const u16x8*)&BloL[(kb * 128 + wn + 32 + lm) * 8]);
      a00 = MFMA(ah0, bh0, a00);
      a01 = MFMA(ah0, bh1, a01);
      a10 = MFMA(ah1, bh0, a10);
      a11 = MFMA(ah1, bh1, a11);
      a00 = MFMA(ah0, bl0, a00);
      a01 = MFMA(ah0, bl1, a01);
      a10 = MFMA(ah1, bl0, a10);
      a11 = MFMA(ah1, bl1, a11);
      a00 = MFMA(al0, bh0, a00);
      a01 = MFMA(al0, bh1, a01);
      a10 = MFMA(al1, bh0, a10);
      a11 = MFMA(al1, bh1, a11);
    }
    __syncthreads();
  }
  // epilogue: C layout col=lane&31, row=(reg&3)+8*(reg>>2)+4*(lane>>5)
  const int colb = n_base + wn;
#pragma unroll
  for (int mt = 0; mt < 2; mt++) {
#pragma unroll
    for (int nt = 0; nt < 2; nt++) {
      f32x16 v = (mt == 0) ? (nt == 0 ? a00 : a01) : (nt == 0 ? a10 : a11);
      int col = colb + nt * 32 + lm;
      float bv = (EPI == 0) ? bias[col] : 0.f;
      int rb = m_base + wm + mt * 32 + 4 * lk;
#pragma unroll
      for (int rg = 0; rg < 16; rg++) {
        int row = rb + (rg & 3) + 8 * (rg >> 2);
        if (row < M) {
          float x = v[rg];
          if (EPI == 0) {
            x = leaky(x + bv);
            unsigned short h, l;
            bsplit(x, h, l);
            Chi[(size_t)row * ldc + col] = h;
            Clo[(size_t)row * ldc + col] = l;
          } else {
            Cf[(size_t)row * ldc + col] = x;
          }
        }
      }
    }
  }
}

// ---------------- split+transpose: src[R][C] f32 -> dst[C][R] bf16 hi/lo ----
__global__ __launch_bounds__(256) void split_transpose(
    const float* __restrict__ src, unsigned short* __restrict__ dsthi,
    unsigned short* __restrict__ dstlo, int R, int C) {
  __shared__ float tile[32][33];
  int tx = threadIdx.x & 31, ty = threadIdx.x >> 5;
  int c0 = blockIdx.x * 32, r0 = blockIdx.y * 32;
#pragma unroll
  for (int i = 0; i < 4; i++)
    tile[ty + i * 8][tx] = src[(size_t)(r0 + ty + i * 8) * C + c0 + tx];
  __syncthreads();
#pragma unroll
  for (int i = 0; i < 4; i++) {
    int c = c0 + ty + i * 8, r = r0 + tx;
    float v = tile[tx][ty + i * 8];
    unsigned short h, l;
    bsplit(v, h, l);
    dsthi[(size_t)c * R + r] = h;
    dstlo[(size_t)c * R + r] = l;
  }
}

// ---------------- small 384x384x384 GEMM (plain C = A@B, fp32) --------------
__global__ __launch_bounds__(256) void gemm384(const float* __restrict__ A,
                                               const float* __restrict__ B,
                                               float* __restrict__ C) {
  __shared__ float As[16][68];
  __shared__ float Bs[16][64];
  const int tid = threadIdx.x;
  const int mb = blockIdx.x * 64;
  const int nb = blockIdx.y * 64;
  float acc[4][4] = {};
  const int arow = tid >> 2, akq = tid & 3;
  const int brow = tid >> 4, bc4 = tid & 15;
  const int m0 = (tid >> 4) * 4, n0 = (tid & 15) * 4;
  for (int kk = 0; kk < 384; kk += 16) {
    float4 av = *(const float4*)&A[(mb + arow) * 384 + kk + akq * 4];
    As[akq * 4 + 0][arow] = av.x;
    As[akq * 4 + 1][arow] = av.y;
    As[akq * 4 + 2][arow] = av.z;
    As[akq * 4 + 3][arow] = av.w;
    *(float4*)&Bs[brow][bc4 * 4] =
        *(const float4*)&B[(kk + brow) * 384 + nb + bc4 * 4];
    __syncthreads();
#pragma unroll
    for (int k = 0; k < 16; k++) {
      float4 a4 = *(const float4*)&As[k][m0];
      float4 b4 = *(const float4*)&Bs[k][n0];
      float a[4] = {a4.x, a4.y, a4.z, a4.w};
      float b[4] = {b4.x, b4.y, b4.z, b4.w};
#pragma unroll
      for (int i = 0; i < 4; i++)
#pragma unroll
        for (int j = 0; j < 4; j++) acc[i][j] = fmaf(a[i], b[j], acc[i][j]);
    }
    __syncthreads();
  }
#pragma unroll
  for (int i = 0; i < 4; i++)
#pragma unroll
    for (int j = 0; j < 4; j++)
      C[(mb + m0 + i) * 384 + nb + n0 + j] = acc[i][j];
}

// u[j] = sum_k T1[k][j]*b_g1[k] ; v[j] = sum_k W_o1[k][j]*b_g2[k] + b_o1[j]
__global__ void uv_kernel(const float* __restrict__ T1,
                          const float* __restrict__ W_o1,
                          const float* __restrict__ b_g1,
                          const float* __restrict__ b_g2,
                          const float* __restrict__ b_o1, float* __restrict__ u,
                          float* __restrict__ v) {
  int j = blockIdx.x * blockDim.x + threadIdx.x;
  if (j < 384) {
    float su = 0.f, sv = 0.f;
    for (int k = 0; k < 384; k++) {
      su = fmaf(T1[k * 384 + j], b_g1[k], su);
      sv = fmaf(W_o1[k * 384 + j], b_g2[k], sv);
    }
    u[j] = su;
    v[j] = sv + b_o1[j];
  }
}

// num/cat -> x0 plane columns 128..383
__global__ __launch_bounds__(256) void numcat_kernel(
    const float* __restrict__ num, const float* __restrict__ cat,
    const float* __restrict__ Wn, const float* __restrict__ bn,
    const float* __restrict__ Wc, const float* __restrict__ bc,
    unsigned short* __restrict__ x0hi, unsigned short* __restrict__ x0lo) {
  int i = blockIdx.x;
  int c = threadIdx.x;
  float val;
  if (c < 128) {
    val = bn[c];
    val = fmaf(num[i * 4 + 0], Wn[0 * 128 + c], val);
    val = fmaf(num[i * 4 + 1], Wn[1 * 128 + c], val);
    val = fmaf(num[i * 4 + 2], Wn[2 * 128 + c], val);
    val = fmaf(num[i * 4 + 3], Wn[3 * 128 + c], val);
  } else {
    int cc = c - 128;
    val = bc[cc];
    val = fmaf(cat[i * 3 + 0], Wc[0 * 128 + cc], val);
    val = fmaf(cat[i * 3 + 1], Wc[1 * 128 + cc], val);
    val = fmaf(cat[i * 3 + 2], Wc[2 * 128 + cc], val);
  }
  val = leaky(val);
  unsigned short h, l;
  bsplit(val, h, l);
  size_t o = (size_t)i * NFEAT + 128 + c;
  x0hi[o] = h;
  x0lo[o] = l;
}

// ---------------- graph prep -----------------------------------------------
__global__ void count_kernel(const int* __restrict__ dst, int* __restrict__ deg,
                             int E) {
  int e = blockIdx.x * blockDim.x + threadIdx.x;
  if (e < E) atomicAdd(&deg[dst[e]], 1);
}

__global__ void scan_reduce(const int* __restrict__ deg,
                            int* __restrict__ partial, int N) {
  __shared__ int sm[512];
  int i = blockIdx.x * 512 + threadIdx.x;
  sm[threadIdx.x] = (i < N) ? deg[i] : 0;
  __syncthreads();
  for (int off = 256; off; off >>= 1) {
    if (threadIdx.x < off) sm[threadIdx.x] += sm[threadIdx.x + off];
    __syncthreads();
  }
  if (threadIdx.x == 0) partial[blockIdx.x] = sm[0];
}

__global__ void scan_top(int* partial, int nb) {
  if (threadIdx.x == 0 && blockIdx.x == 0) {
    int run = 0;
    for (int b = 0; b < nb; b++) {
      int t = partial[b];
      partial[b] = run;
      run += t;
    }
  }
}

__global__ void scan_down(const int* __restrict__ deg,
                          const int* __restrict__ partial,
                          int* __restrict__ offsets, int* __restrict__ cursor,
                          int N, int E) {
  __shared__ int sm[512];
  int t = threadIdx.x;
  int i = blockIdx.x * 512 + t;
  int val = (i < N) ? deg[i] : 0;
  sm[t] = val;
  __syncthreads();
  for (int off = 1; off < 512; off <<= 1) {
    int add = (t >= off) ? sm[t - off] : 0;
    __syncthreads();
    sm[t] += add;
    __syncthreads();
  }
  if (i < N) {
    int ex = partial[blockIdx.x] + sm[t] - val;
    offsets[i] = ex;
    cursor[i] = ex;
  }
  if (i == 0) offsets[N] = E;
}

__global__ void dinv_kernel(const int* __restrict__ deg,
                            float* __restrict__ dinv, int N) {
  int i = blockIdx.x * blockDim.x + threadIdx.x;
  if (i < N) dinv[i] = 1.0f / sqrtf((float)deg[i] + 1.0f);
}

// csr_off stores src*NFEAT (premultiplied row offset)
__global__ void fill_kernel(const int* __restrict__ src,
                            const int* __restrict__ dst,
                            int* __restrict__ cursor,
                            int* __restrict__ csr_off,
                            float* __restrict__ csr_w,
                            const float* __restrict__ dinv, int E) {
  int e = blockIdx.x * blockDim.x + threadIdx.x;
  if (e < E) {
    int s = src[e], d = dst[e];
    int slot = atomicAdd(&cursor[d], 1);
    csr_off[slot] = s * NFEAT;
    csr_w[slot] = dinv[s] * dinv[d];
  }
}

// ---------------- aggregation: xout = Ahat @ xin ----------------------------
// 192 threads, float2 per lane. WRITE_S: also s_i = (Ahat @ 1)_i.
// FINAL: leaky(acc + s_i*u + v) -> dot W_o2 -> out[i][0:2]
template <int WRITE_S, int FINAL>
__global__ __launch_bounds__(192) void agg_kernel(
    const float* __restrict__ xin, float* __restrict__ xout,
    const int* __restrict__ offsets, const int* __restrict__ csr_off,
    const float* __restrict__ csr_w, const float* __restrict__ dinv,
    float* __restrict__ sout, const float* __restrict__ svec,
    const float* __restrict__ uvec, const float* __restrict__ vvec,
    const float* __restrict__ W_o2, const float* __restrict__ b_o2,
    float* __restrict__ out) {
  int i = blockIdx.x;
  int t = threadIdx.x;
  int ff = 2 * t;
  int beg = offsets[i], end = offsets[i + 1];
  float di = dinv[i];
  float dii = di * di;
  float2 xs = *(const float2*)&xin[(size_t)i * NFEAT + ff];
  float A0x = dii * xs.x, A0y = dii * xs.y;
  float A1x = 0.f, A1y = 0.f, A2x = 0.f, A2y = 0.f, A3x = 0.f, A3y = 0.f;
  float wsum = dii;
  __shared__ int ssrc[192];
  __shared__ float sw[192];
  for (int j0 = beg; j0 < end; j0 += 192) {
    int cnt = min(192, end - j0);
    if (t < cnt) {
      ssrc[t] = csr_off[j0 + t];
      sw[t] = csr_w[j0 + t];
    }
    __syncthreads();
    int j = 0;
    for (; j + 8 <= cnt; j += 8) {
      int o0 = ssrc[j + 0], o1 = ssrc[j + 1], o2 = ssrc[j + 2],
          o3 = ssrc[j + 3];
      int o4 = ssrc[j + 4], o5 = ssrc[j + 5], o6 = ssrc[j + 6],
          o7 = ssrc[j + 7];
      float w0 = sw[j + 0], w1 = sw[j + 1], w2 = sw[j + 2], w3 = sw[j + 3];
      float w4 = sw[j + 4], w5 = sw[j + 5], w6 = sw[j + 6], w7 = sw[j + 7];
      float2 v0 = *(const float2*)&xin[o0 + ff];
      float2 v1 = *(const float2*)&xin[o1 + ff];
      float2 v2 = *(const float2*)&xin[o2 + ff];
      float2 v3 = *(const float2*)&xin[o3 + ff];
      float2 v4 = *(const float2*)&xin[o4 + ff];
      float2 v5 = *(const float2*)&xin[o5 + ff];
      float2 v6 = *(const float2*)&xin[o6 + ff];
      float2 v7 = *(const float2*)&xin[o7 + ff];
      A0x = fmaf(w0, v0.x, A0x);
      A0y = fmaf(w0, v0.y, A0y);
      A1x = fmaf(w1, v1.x, A1x);
      A1y = fmaf(w1, v1.y, A1y);
      A2x = fmaf(w2, v2.x, A2x);
      A2y = fmaf(w2, v2.y, A2y);
      A3x = fmaf(w3, v3.x, A3x);
      A3y = fmaf(w3, v3.y, A3y);
      A0x = fmaf(w4, v4.x, A0x);
      A0y = fmaf(w4, v4.y, A0y);
      A1x = fmaf(w5, v5.x, A1x);
      A1y = fmaf(w5, v5.y, A1y);
      A2x = fmaf(w6, v6.x, A2x);
      A2y = fmaf(w6, v6.y, A2y);
      A3x = fmaf(w7, v7.x, A3x);
      A3y = fmaf(w7, v7.y, A3y);
      if (WRITE_S) wsum += ((w0 + w1) + (w2 + w3)) + ((w4 + w5) + (w6 + w7));
    }
    for (; j < cnt; j++) {
      float wj = sw[j];
      float2 vj = *(const float2*)&xin[ssrc[j] + ff];
      A0x = fmaf(wj, vj.x, A0x);
      A0y = fmaf(wj, vj.y, A0y);
      if (WRITE_S) wsum += wj;
    }
    __syncthreads();
  }
  float ax = (A0x + A1x) + (A2x + A3x);
  float ay = (A0y + A1y) + (A2y + A3y);
  if (!FINAL) {
    float2 r;
    r.x = ax;
    r.y = ay;
    *(float2*)&xout[(size_t)i * NFEAT + ff] = r;
    if (WRITE_S && t == 0) sout[i] = wsum;
  } else {
    float si = svec[i];
    float v0 = leaky(ax + si * uvec[ff + 0] + vvec[ff + 0]);
    float v1 = leaky(ay + si * uvec[ff + 1] + vvec[ff + 1]);
    float c0 = v0 * W_o2[(ff + 0) * 2 + 0] + v1 * W_o2[(ff + 1) * 2 + 0];
    float c1 = v0 * W_o2[(ff + 0) * 2 + 1] + v1 * W_o2[(ff + 1) * 2 + 1];
#pragma unroll
    for (int off2 = 32; off2; off2 >>= 1) {
      c0 += __shfl_down(c0, off2, 64);
      c1 += __shfl_down(c1, off2, 64);
    }
    __shared__ float red[3][2];
    int wid = t >> 6, lane2 = t & 63;
    if (lane2 == 0) {
      red[wid][0] = c0;
      red[wid][1] = c1;
    }
    __syncthreads();
    if (t == 0) {
      out[i * 2 + 0] = red[0][0] + red[1][0] + red[2][0] + b_o2[0];
      out[i * 2 + 1] = red[0][1] + red[1][1] + red[2][1] + b_o2[1];
    }
  }
}

extern "C" void kernel_launch(void* const* d_in, const int* in_sizes, int n_in,
                              void* d_out, int out_size, void* d_ws,
                              size_t ws_size, hipStream_t stream) {
  const float* des = (const float*)d_in[0];
  // d_in[1] = tweet : unused by the reference
  const float* num_prop = (const float*)d_in[2];
  const float* cat_prop = (const float*)d_in[3];
  const int* edge = (const int*)d_in[4];
  const float* W_des = (const float*)d_in[5];
  const float* b_des = (const float*)d_in[6];
  const float* W_num = (const float*)d_in[7];
  const float* b_num = (const float*)d_in[8];
  const float* W_cat = (const float*)d_in[9];
  const float* b_cat = (const float*)d_in[10];
  const float* W_in = (const float*)d_in[11];
  const float* b_in = (const float*)d_in[12];
  const float* W_g1 = (const float*)d_in[13];
  const float* b_g1 = (const float*)d_in[14];
  const float* W_g2 = (const float*)d_in[15];
  const float* b_g2 = (const float*)d_in[16];
  const float* W_o1 = (const float*)d_in[17];
  const float* b_o1 = (const float*)d_in[18];
  const float* W_o2 = (const float*)d_in[19];
  const float* b_o2 = (const float*)d_in[20];
  float* out = (float*)d_out;

  const int N = in_sizes[0] / DESK;  // 50000
  const int E = in_sizes[4] / 2;     // 800000
  const int* esrc = edge;
  const int* edst = edge + E;

  // workspace layout
  char* ws = (char*)d_ws;
  size_t off = 0;
  auto alloc = [&](size_t n) {
    off = (off + 255) & ~(size_t)255;
    size_t o = off;
    off += n;
    return o;
  };
  float* bufA = (float*)(ws + alloc((size_t)N * NFEAT * 4));  // x0 planes / y
  float* bufB = (float*)(ws + alloc((size_t)N * NFEAT * 4));  // x1 planes / w1
  int* deg = (int*)(ws + alloc((size_t)N * 4));
  int* offsets = (int*)(ws + alloc((size_t)(N + 1) * 4));
  int* cursor = (int*)(ws + alloc((size_t)N * 4));
  int* partial = (int*)(ws + alloc(1024 * 4));
  float* dinv = (float*)(ws + alloc((size_t)N * 4));
  float* svec = (float*)(ws + alloc((size_t)N * 4));
  int* csr_off = (int*)(ws + alloc((size_t)E * 4));
  float* csr_w = (float*)(ws + alloc((size_t)E * 4));
  float* T1 = (float*)(ws + alloc(384 * 384 * 4));
  float* Mmat = (float*)(ws + alloc(384 * 384 * 4));
  float* uvec = (float*)(ws + alloc(384 * 4));
  float* vvec = (float*)(ws + alloc(384 * 4));
  unsigned short* WdThi = (unsigned short*)(ws + alloc(768 * 128 * 2));
  unsigned short* WdTlo = (unsigned short*)(ws + alloc(768 * 128 * 2));
  unsigned short* WiThi = (unsigned short*)(ws + alloc(384 * 384 * 2));
  unsigned short* WiTlo = (unsigned short*)(ws + alloc(384 * 384 * 2));
  unsigned short* MmThi = (unsigned short*)(ws + alloc(384 * 384 * 2));
  unsigned short* MmTlo = (unsigned short*)(ws + alloc(384 * 384 * 2));
  (void)ws_size;
  (void)n_in;
  (void)out_size;

  unsigned short* x0hi = (unsigned short*)bufA;
  unsigned short* x0lo = x0hi + (size_t)N * NFEAT;
  unsigned short* x1hi = (unsigned short*)bufB;
  unsigned short* x1lo = x1hi + (size_t)N * NFEAT;
  float* yb = bufA;
  float* w1 = bufB;

  hipMemsetAsync(deg, 0, (size_t)N * 4, stream);

  // small precomputes: T1 = W_g2 @ W_o1 ; Mmat = W_g1 @ T1 ; u, v; B^T splits
  dim3 g6(6, 6);
  gemm384<<<g6, 256, 0, stream>>>(W_g2, W_o1, T1);
  gemm384<<<g6, 256, 0, stream>>>(W_g1, T1, Mmat);
  uv_kernel<<<2, 256, 0, stream>>>(T1, W_o1, b_g1, b_g2, b_o1, uvec, vvec);
  split_transpose<<<dim3(4, 24), 256, 0, stream>>>(W_des, WdThi, WdTlo, 768,
                                                   128);
  split_transpose<<<dim3(12, 12), 256, 0, stream>>>(W_in, WiThi, WiTlo, 384,
                                                    384);
  split_transpose<<<dim3(12, 12), 256, 0, stream>>>(Mmat, MmThi, MmTlo, 384,
                                                    384);

  const int MT = (N + 127) / 128;  // 391
  // x0 cols 0..127 = leaky(des @ W_des + b_des) -> bf16 hi/lo planes
  mfma_gemm<1, 0><<<dim3(MT, 1), 256, 0, stream>>>(
      des, nullptr, nullptr, WdThi, WdTlo, nullptr, x0hi, x0lo, b_des, N, DESK,
      NFEAT);
  // x0 cols 128..383
  numcat_kernel<<<N, 256, 0, stream>>>(num_prop, cat_prop, W_num, b_num, W_cat,
                                       b_cat, x0hi, x0lo);
  // x1 = leaky(x0 @ W_in + b_in) -> planes
  mfma_gemm<0, 0><<<dim3(MT, 3), 256, 0, stream>>>(
      nullptr, x0hi, x0lo, WiThi, WiTlo, nullptr, x1hi, x1lo, b_in, N, NFEAT,
      NFEAT);
  // y = x1 @ Mmat -> fp32 (overwrites x0 planes region)
  mfma_gemm<0, 1><<<dim3(MT, 3), 256, 0, stream>>>(
      nullptr, x1hi, x1lo, MmThi, MmTlo, yb, nullptr, nullptr, nullptr, N,
      NFEAT, NFEAT);

  // graph prep
  const int EB = (E + 255) / 256;
  count_kernel<<<EB, 256, 0, stream>>>(edst, deg, E);
  const int NB = (N + 511) / 512;
  scan_reduce<<<NB, 512, 0, stream>>>(deg, partial, N);
  scan_top<<<1, 64, 0, stream>>>(partial, NB);
  scan_down<<<NB, 512, 0, stream>>>(deg, partial, offsets, cursor, N, E);
  dinv_kernel<<<(N + 255) / 256, 256, 0, stream>>>(deg, dinv, N);
  fill_kernel<<<EB, 256, 0, stream>>>(esrc, edst, cursor, csr_off, csr_w, dinv,
                                      E);

  // w1 = Ahat @ y (also s = Ahat @ 1) ; then fused final:
  // out = (leaky(Ahat @ w1 + s*u + v)) @ W_o2 + b_o2
  agg_kernel<1, 0><<<N, 192, 0, stream>>>(yb, w1, offsets, csr_off, csr_w, dinv,
                                          svec, nullptr, nullptr, nullptr,
                                          nullptr, nullptr, nullptr);
  agg_kernel<0, 1><<<N, 192, 0, stream>>>(w1, nullptr, offsets, csr_off, csr_w,
                                          dinv, nullptr, svec, uvec, vvec, W_o2,
                                          b_o2, out);
}

// Round 4
// 960.033 us; speedup vs baseline: 1.4384x; 1.1393x over previous
//
#include <hip/hip_runtime.h>
#include <hip/hip_bf16.h>
#include <cstdint>

#define NFEAT 384
#define DESK 768
#define THIRD 128

typedef __bf16 bf16x8 __attribute__((ext_vector_type(8)));
typedef unsigned short u16x8 __attribute__((ext_vector_type(8)));
typedef unsigned short u16x4 __attribute__((ext_vector_type(4)));
typedef float f32x16 __attribute__((ext_vector_type(16)));
typedef _Float16 h16x2 __attribute__((ext_vector_type(2)));

__device__ __forceinline__ float leaky(float x) { return x > 0.f ? x : 0.01f * x; }

__device__ __forceinline__ unsigned short bfhi(float x) {
  unsigned int u = __float_as_uint(x);
  u += 0x7fffu + ((u >> 16) & 1u);
  return (unsigned short)(u >> 16);
}
__device__ __forceinline__ float bf2f(unsigned short h) {
  return __uint_as_float(((unsigned int)h) << 16);
}
__device__ __forceinline__ void bsplit(float x, unsigned short& h,
                                       unsigned short& l) {
  h = bfhi(x);
  l = bfhi(x - bf2f(h));
}

#define MFMA(a, b, c) __builtin_amdgcn_mfma_f32_32x32x16_bf16(a, b, c, 0, 0, 0)

// ---------------- split-bf16 MFMA GEMM -------------------------------------
// C[M x N] = A[M x K] @ B[K x N], N-tile=128 per blockIdx.y, BM=128, BK=32.
// A: fp32 (AFP32=1, split in staging) or bf16 hi/lo planes.
// B: pre-split transposed planes BT[N][K] (hi/lo bf16).
// EPI 0: leaky(x+bias) -> bf16 hi/lo planes Chi/Clo
// EPI 1: plain -> fp16 Ch16
template <int AFP32, int EPI>
__global__ __launch_bounds__(256, 2) void mfma_gemm(
    const float* __restrict__ Af, const unsigned short* __restrict__ Ahi,
    const unsigned short* __restrict__ Alo,
    const unsigned short* __restrict__ BThi,
    const unsigned short* __restrict__ BTlo, _Float16* __restrict__ Ch16,
    unsigned short* __restrict__ Chi, unsigned short* __restrict__ Clo,
    const float* __restrict__ bias, int M, int K, int ldc) {
  __shared__ unsigned short AhiL[4 * 128 * 8];
  __shared__ unsigned short AloL[4 * 128 * 8];
  __shared__ unsigned short BhiL[4 * 128 * 8];
  __shared__ unsigned short BloL[4 * 128 * 8];
  const int tid = threadIdx.x;
  const int lane = tid & 63;
  const int w = tid >> 6;
  const int wm = (w >> 1) * 64, wn = (w & 1) * 64;
  const int lm = lane & 31, lk = lane >> 5;
  const int m_base = blockIdx.x * 128, n_base = blockIdx.y * 128;
  f32x16 a00 = {0.f, 0.f, 0.f, 0.f, 0.f, 0.f, 0.f, 0.f,
                0.f, 0.f, 0.f, 0.f, 0.f, 0.f, 0.f, 0.f};
  f32x16 a01 = a00, a10 = a00, a11 = a00;

  for (int kt = 0; kt < K; kt += 32) {
    if (AFP32) {
#pragma unroll
      for (int it = 0; it < 4; it++) {
        int r = (tid >> 3) + it * 32;
        int q = tid & 7;
        int gr = m_base + r;
        float4 av = make_float4(0.f, 0.f, 0.f, 0.f);
        if (gr < M) av = *(const float4*)&Af[(size_t)gr * K + kt + q * 4];
        unsigned short h0, h1, h2, h3, l0, l1, l2, l3;
        bsplit(av.x, h0, l0);
        bsplit(av.y, h1, l1);
        bsplit(av.z, h2, l2);
        bsplit(av.w, h3, l3);
        int base = ((q >> 1) * 128 + r) * 8 + (q & 1) * 4;
        u16x4 th;
        th.x = h0; th.y = h1; th.z = h2; th.w = h3;
        u16x4 tl;
        tl.x = l0; tl.y = l1; tl.z = l2; tl.w = l3;
        *(u16x4*)&AhiL[base] = th;
        *(u16x4*)&AloL[base] = tl;
      }
    } else {
#pragma unroll
      for (int it = 0; it < 2; it++) {
        int r = (tid >> 2) + it * 64;
        int kb = tid & 3;
        int gr = m_base + r;
        u16x8 vh = {0, 0, 0, 0, 0, 0, 0, 0};
        u16x8 vl = {0, 0, 0, 0, 0, 0, 0, 0};
        if (gr < M) {
          vh = *(const u16x8*)&Ahi[(size_t)gr * K + kt + kb * 8];
          vl = *(const u16x8*)&Alo[(size_t)gr * K + kt + kb * 8];
        }
        *(u16x8*)&AhiL[(kb * 128 + r) * 8] = vh;
        *(u16x8*)&AloL[(kb * 128 + r) * 8] = vl;
      }
    }
#pragma unroll
    for (int it = 0; it < 2; it++) {
      int n = (tid >> 2) + it * 64;
      int kb = tid & 3;
      *(u16x8*)&BhiL[(kb * 128 + n) * 8] =
          *(const u16x8*)&BThi[(size_t)(n_base + n) * K + kt + kb * 8];
      *(u16x8*)&BloL[(kb * 128 + n) * 8] =
          *(const u16x8*)&BTlo[(size_t)(n_base + n) * K + kt + kb * 8];
    }
    __syncthreads();
#pragma unroll
    for (int ks = 0; ks < 2; ks++) {
      int kb = 2 * ks + lk;
      bf16x8 ah0 = __builtin_bit_cast(
          bf16x8, *(const u16x8*)&AhiL[(kb * 128 + wm + lm) * 8]);
      bf16x8 ah1 = __builtin_bit_cast(
          bf16x8, *(const u16x8*)&AhiL[(kb * 128 + wm + 32 + lm) * 8]);
      bf16x8 al0 = __builtin_bit_cast(
          bf16x8, *(const u16x8*)&AloL[(kb * 128 + wm + lm) * 8]);
      bf16x8 al1 = __builtin_bit_cast(
          bf16x8, *(const u16x8*)&AloL[(kb * 128 + wm + 32 + lm) * 8]);
      bf16x8 bh0 = __builtin_bit_cast(
          bf16x8, *(const u16x8*)&BhiL[(kb * 128 + wn + lm) * 8]);
      bf16x8 bh1 = __builtin_bit_cast(
          bf16x8, *(const u16x8*)&BhiL[(kb * 128 + wn + 32 + lm) * 8]);
      bf16x8 bl0 = __builtin_bit_cast(
          bf16x8, *(const u16x8*)&BloL[(kb * 128 + wn + lm) * 8]);
      bf16x8 bl1 = __builtin_bit_cast(
          bf16x8, *(const u16x8*)&BloL[(kb * 128 + wn + 32 + lm) * 8]);
      a00 = MFMA(ah0, bh0, a00);
      a01 = MFMA(ah0, bh1, a01);
      a10 = MFMA(ah1, bh0, a10);
      a11 = MFMA(ah1, bh1, a11);
      a00 = MFMA(ah0, bl0, a00);
      a01 = MFMA(ah0, bl1, a01);
      a10 = MFMA(ah1, bl0, a10);
      a11 = MFMA(ah1, bl1, a11);
      a00 = MFMA(al0, bh0, a00);
      a01 = MFMA(al0, bh1, a01);
      a10 = MFMA(al1, bh0, a10);
      a11 = MFMA(al1, bh1, a11);
    }
    __syncthreads();
  }
  // epilogue: C layout col=lane&31, row=(reg&3)+8*(reg>>2)+4*(lane>>5)
  const int colb = n_base + wn;
#pragma unroll
  for (int mt = 0; mt < 2; mt++) {
#pragma unroll
    for (int nt = 0; nt < 2; nt++) {
      f32x16 v = (mt == 0) ? (nt == 0 ? a00 : a01) : (nt == 0 ? a10 : a11);
      int col = colb + nt * 32 + lm;
      float bv = (EPI == 0) ? bias[col] : 0.f;
      int rb = m_base + wm + mt * 32 + 4 * lk;
#pragma unroll
      for (int rg = 0; rg < 16; rg++) {
        int row = rb + (rg & 3) + 8 * (rg >> 2);
        if (row < M) {
          float x = v[rg];
          if (EPI == 0) {
            x = leaky(x + bv);
            unsigned short h, l;
            bsplit(x, h, l);
            Chi[(size_t)row * ldc + col] = h;
            Clo[(size_t)row * ldc + col] = l;
          } else {
            Ch16[(size_t)row * ldc + col] = (_Float16)x;
          }
        }
      }
    }
  }
}

// --------- batched split+transpose: src[R][C] f32 -> dst[C][R] bf16 hi/lo ---
// z=0: W_des 768x128 ; z=1: W_in 384x384 ; z=2: Mmat 384x384
__global__ __launch_bounds__(256) void split_transpose_b(
    const float* __restrict__ s0, unsigned short* __restrict__ h0,
    unsigned short* __restrict__ l0, const float* __restrict__ s1,
    unsigned short* __restrict__ h1, unsigned short* __restrict__ l1,
    const float* __restrict__ s2, unsigned short* __restrict__ h2,
    unsigned short* __restrict__ l2) {
  int z = blockIdx.z;
  const float* src = z == 0 ? s0 : (z == 1 ? s1 : s2);
  unsigned short* dsthi = z == 0 ? h0 : (z == 1 ? h1 : h2);
  unsigned short* dstlo = z == 0 ? l0 : (z == 1 ? l1 : l2);
  int R = z == 0 ? 768 : 384;
  int C = z == 0 ? 128 : 384;
  int c0 = blockIdx.x * 32, r0 = blockIdx.y * 32;
  if (c0 >= C || r0 >= R) return;
  __shared__ float tile[32][33];
  int tx = threadIdx.x & 31, ty = threadIdx.x >> 5;
#pragma unroll
  for (int i = 0; i < 4; i++)
    tile[ty + i * 8][tx] = src[(size_t)(r0 + ty + i * 8) * C + c0 + tx];
  __syncthreads();
#pragma unroll
  for (int i = 0; i < 4; i++) {
    int c = c0 + ty + i * 8, r = r0 + tx;
    float v = tile[tx][ty + i * 8];
    unsigned short h, l;
    bsplit(v, h, l);
    dsthi[(size_t)c * R + r] = h;
    dstlo[(size_t)c * R + r] = l;
  }
}

// ---------------- small 384x384x384 GEMM (plain C = A@B, fp32) --------------
__global__ __launch_bounds__(256) void gemm384(const float* __restrict__ A,
                                               const float* __restrict__ B,
                                               float* __restrict__ C) {
  __shared__ float As[16][68];
  __shared__ float Bs[16][64];
  const int tid = threadIdx.x;
  const int mb = blockIdx.x * 64;
  const int nb = blockIdx.y * 64;
  float acc[4][4] = {};
  const int arow = tid >> 2, akq = tid & 3;
  const int brow = tid >> 4, bc4 = tid & 15;
  const int m0 = (tid >> 4) * 4, n0 = (tid & 15) * 4;
  for (int kk = 0; kk < 384; kk += 16) {
    float4 av = *(const float4*)&A[(mb + arow) * 384 + kk + akq * 4];
    As[akq * 4 + 0][arow] = av.x;
    As[akq * 4 + 1][arow] = av.y;
    As[akq * 4 + 2][arow] = av.z;
    As[akq * 4 + 3][arow] = av.w;
    *(float4*)&Bs[brow][bc4 * 4] =
        *(const float4*)&B[(kk + brow) * 384 + nb + bc4 * 4];
    __syncthreads();
#pragma unroll
    for (int k = 0; k < 16; k++) {
      float4 a4 = *(const float4*)&As[k][m0];
      float4 b4 = *(const float4*)&Bs[k][n0];
      float a[4] = {a4.x, a4.y, a4.z, a4.w};
      float b[4] = {b4.x, b4.y, b4.z, b4.w};
#pragma unroll
      for (int i = 0; i < 4; i++)
#pragma unroll
        for (int j = 0; j < 4; j++) acc[i][j] = fmaf(a[i], b[j], acc[i][j]);
    }
    __syncthreads();
  }
#pragma unroll
  for (int i = 0; i < 4; i++)
#pragma unroll
    for (int j = 0; j < 4; j++)
      C[(mb + m0 + i) * 384 + nb + n0 + j] = acc[i][j];
}

// u[j] = sum_k T1[k][j]*b_g1[k] ; v[j] = sum_k W_o1[k][j]*b_g2[k] + b_o1[j]
__global__ void uv_kernel(const float* __restrict__ T1,
                          const float* __restrict__ W_o1,
                          const float* __restrict__ b_g1,
                          const float* __restrict__ b_g2,
                          const float* __restrict__ b_o1, float* __restrict__ u,
                          float* __restrict__ v) {
  int j = blockIdx.x * blockDim.x + threadIdx.x;
  if (j < 384) {
    float su = 0.f, sv = 0.f;
    for (int k = 0; k < 384; k++) {
      su = fmaf(T1[k * 384 + j], b_g1[k], su);
      sv = fmaf(W_o1[k * 384 + j], b_g2[k], sv);
    }
    u[j] = su;
    v[j] = sv + b_o1[j];
  }
}

// num/cat -> x0 plane columns 128..383 (persistent grid-stride over rows)
__global__ __launch_bounds__(256) void numcat_kernel(
    const float* __restrict__ num, const float* __restrict__ cat,
    const float* __restrict__ Wn, const float* __restrict__ bn,
    const float* __restrict__ Wc, const float* __restrict__ bc,
    unsigned short* __restrict__ x0hi, unsigned short* __restrict__ x0lo,
    int N) {
  int c = threadIdx.x;
  for (int i = blockIdx.x; i < N; i += gridDim.x) {
    float val;
    if (c < 128) {
      val = bn[c];
      val = fmaf(num[i * 4 + 0], Wn[0 * 128 + c], val);
      val = fmaf(num[i * 4 + 1], Wn[1 * 128 + c], val);
      val = fmaf(num[i * 4 + 2], Wn[2 * 128 + c], val);
      val = fmaf(num[i * 4 + 3], Wn[3 * 128 + c], val);
    } else {
      int cc = c - 128;
      val = bc[cc];
      val = fmaf(cat[i * 3 + 0], Wc[0 * 128 + cc], val);
      val = fmaf(cat[i * 3 + 1], Wc[1 * 128 + cc], val);
      val = fmaf(cat[i * 3 + 2], Wc[2 * 128 + cc], val);
    }
    val = leaky(val);
    unsigned short h, l;
    bsplit(val, h, l);
    size_t o = (size_t)i * NFEAT + 128 + c;
    x0hi[o] = h;
    x0lo[o] = l;
  }
}

// ---------------- graph prep -----------------------------------------------
__global__ void count_kernel(const int* __restrict__ dst, int* __restrict__ deg,
                             int E) {
  int e = blockIdx.x * blockDim.x + threadIdx.x;
  if (e < E) atomicAdd(&deg[dst[e]], 1);
}

__global__ void scan_reduce(const int* __restrict__ deg,
                            int* __restrict__ partial, int N) {
  __shared__ int sm[512];
  int i = blockIdx.x * 512 + threadIdx.x;
  sm[threadIdx.x] = (i < N) ? deg[i] : 0;
  __syncthreads();
  for (int off = 256; off; off >>= 1) {
    if (threadIdx.x < off) sm[threadIdx.x] += sm[threadIdx.x + off];
    __syncthreads();
  }
  if (threadIdx.x == 0) partial[blockIdx.x] = sm[0];
}

__global__ void scan_top(int* partial, int nb) {
  if (threadIdx.x == 0 && blockIdx.x == 0) {
    int run = 0;
    for (int b = 0; b < nb; b++) {
      int t = partial[b];
      partial[b] = run;
      run += t;
    }
  }
}

// exclusive scan + offsets/cursor + fused dinv
__global__ void scan_down(const int* __restrict__ deg,
                          const int* __restrict__ partial,
                          int* __restrict__ offsets, int* __restrict__ cursor,
                          float* __restrict__ dinv, int N, int E) {
  __shared__ int sm[512];
  int t = threadIdx.x;
  int i = blockIdx.x * 512 + t;
  int val = (i < N) ? deg[i] : 0;
  sm[t] = val;
  __syncthreads();
  for (int off = 1; off < 512; off <<= 1) {
    int add = (t >= off) ? sm[t - off] : 0;
    __syncthreads();
    sm[t] += add;
    __syncthreads();
  }
  if (i < N) {
    int ex = partial[blockIdx.x] + sm[t] - val;
    offsets[i] = ex;
    cursor[i] = ex;
    dinv[i] = 1.0f / sqrtf((float)val + 1.0f);
  }
  if (i == 0) offsets[N] = E;
}

// csr_off stores src*NFEAT (premultiplied row offset, fp16-element units)
__global__ void fill_kernel(const int* __restrict__ src,
                            const int* __restrict__ dst,
                            int* __restrict__ cursor,
                            int* __restrict__ csr_off,
                            float* __restrict__ csr_w,
                            const float* __restrict__ dinv, int E) {
  int e = blockIdx.x * blockDim.x + threadIdx.x;
  if (e < E) {
    int s = src[e], d = dst[e];
    int slot = atomicAdd(&cursor[d], 1);
    csr_off[slot] = s * NFEAT;
    csr_w[slot] = dinv[s] * dinv[d];
  }
}

// ---------------- aggregation: xout = Ahat @ xin (fp16 payload) -------------
// persistent grid-stride over rows; 192 threads, half2 per lane.
// WRITE_S: also s_i = (Ahat @ 1)_i.
// FINAL: leaky(acc + s_i*u + v) -> dot W_o2 -> out[i][0:2]
template <int WRITE_S, int FINAL>
__global__ __launch_bounds__(192) void agg_kernel(
    const _Float16* __restrict__ xin, _Float16* __restrict__ xout,
    const int* __restrict__ offsets, const int* __restrict__ csr_off,
    const float* __restrict__ csr_w, const float* __restrict__ dinv,
    float* __restrict__ sout, const float* __restrict__ svec,
    const float* __restrict__ uvec, const float* __restrict__ vvec,
    const float* __restrict__ W_o2, const float* __restrict__ b_o2,
    float* __restrict__ out, int N) {
  const int t = threadIdx.x;
  const int ff = 2 * t;
  __shared__ int ssrc[192];
  __shared__ float sw[192];
  __shared__ float red[3][2];
  float u0 = 0.f, u1 = 0.f, vc0 = 0.f, vc1 = 0.f;
  float w00 = 0.f, w01 = 0.f, w10 = 0.f, w11 = 0.f, bo0 = 0.f, bo1 = 0.f;
  if (FINAL) {
    u0 = uvec[ff];
    u1 = uvec[ff + 1];
    vc0 = vvec[ff];
    vc1 = vvec[ff + 1];
    w00 = W_o2[ff * 2 + 0];
    w01 = W_o2[ff * 2 + 1];
    w10 = W_o2[(ff + 1) * 2 + 0];
    w11 = W_o2[(ff + 1) * 2 + 1];
    bo0 = b_o2[0];
    bo1 = b_o2[1];
  }
  for (int i = blockIdx.x; i < N; i += gridDim.x) {
    int beg = offsets[i], end = offsets[i + 1];
    float di = dinv[i];
    float dii = di * di;
    h16x2 xs = *(const h16x2*)&xin[(size_t)i * NFEAT + ff];
    float A0x = dii * (float)xs.x, A0y = dii * (float)xs.y;
    float A1x = 0.f, A1y = 0.f, A2x = 0.f, A2y = 0.f, A3x = 0.f, A3y = 0.f;
    float wsum = dii;
    for (int j0 = beg; j0 < end; j0 += 192) {
      int cnt = min(192, end - j0);
      if (t < cnt) {
        ssrc[t] = csr_off[j0 + t];
        sw[t] = csr_w[j0 + t];
      }
      __syncthreads();
      int j = 0;
      for (; j + 8 <= cnt; j += 8) {
        int o0 = ssrc[j + 0], o1 = ssrc[j + 1], o2 = ssrc[j + 2],
            o3 = ssrc[j + 3];
        int o4 = ssrc[j + 4], o5 = ssrc[j + 5], o6 = ssrc[j + 6],
            o7 = ssrc[j + 7];
        float w0 = sw[j + 0], w1 = sw[j + 1], w2 = sw[j + 2], w3 = sw[j + 3];
        float w4 = sw[j + 4], w5 = sw[j + 5], w6 = sw[j + 6], w7 = sw[j + 7];
        h16x2 v0 = *(const h16x2*)&xin[o0 + ff];
        h16x2 v1 = *(const h16x2*)&xin[o1 + ff];
        h16x2 v2 = *(const h16x2*)&xin[o2 + ff];
        h16x2 v3 = *(const h16x2*)&xin[o3 + ff];
        h16x2 v4 = *(const h16x2*)&xin[o4 + ff];
        h16x2 v5 = *(const h16x2*)&xin[o5 + ff];
        h16x2 v6 = *(const h16x2*)&xin[o6 + ff];
        h16x2 v7 = *(const h16x2*)&xin[o7 + ff];
        A0x = fmaf(w0, (float)v0.x, A0x);
        A0y = fmaf(w0, (float)v0.y, A0y);
        A1x = fmaf(w1, (float)v1.x, A1x);
        A1y = fmaf(w1, (float)v1.y, A1y);
        A2x = fmaf(w2, (float)v2.x, A2x);
        A2y = fmaf(w2, (float)v2.y, A2y);
        A3x = fmaf(w3, (float)v3.x, A3x);
        A3y = fmaf(w3, (float)v3.y, A3y);
        A0x = fmaf(w4, (float)v4.x, A0x);
        A0y = fmaf(w4, (float)v4.y, A0y);
        A1x = fmaf(w5, (float)v5.x, A1x);
        A1y = fmaf(w5, (float)v5.y, A1y);
        A2x = fmaf(w6, (float)v6.x, A2x);
        A2y = fmaf(w6, (float)v6.y, A2y);
        A3x = fmaf(w7, (float)v7.x, A3x);
        A3y = fmaf(w7, (float)v7.y, A3y);
        if (WRITE_S) wsum += ((w0 + w1) + (w2 + w3)) + ((w4 + w5) + (w6 + w7));
      }
      for (; j < cnt; j++) {
        float wj = sw[j];
        h16x2 vj = *(const h16x2*)&xin[ssrc[j] + ff];
        A0x = fmaf(wj, (float)vj.x, A0x);
        A0y = fmaf(wj, (float)vj.y, A0y);
        if (WRITE_S) wsum += wj;
      }
      __syncthreads();
    }
    float ax = (A0x + A1x) + (A2x + A3x);
    float ay = (A0y + A1y) + (A2y + A3y);
    if (!FINAL) {
      h16x2 r;
      r.x = (_Float16)ax;
      r.y = (_Float16)ay;
      *(h16x2*)&xout[(size_t)i * NFEAT + ff] = r;
      if (WRITE_S && t == 0) sout[i] = wsum;
    } else {
      float si = svec[i];
      float q0 = leaky(ax + si * u0 + vc0);
      float q1 = leaky(ay + si * u1 + vc1);
      float c0 = q0 * w00 + q1 * w10;
      float c1 = q0 * w01 + q1 * w11;
#pragma unroll
      for (int off2 = 32; off2; off2 >>= 1) {
        c0 += __shfl_down(c0, off2, 64);
        c1 += __shfl_down(c1, off2, 64);
      }
      int wid = t >> 6, lane2 = t & 63;
      if (lane2 == 0) {
        red[wid][0] = c0;
        red[wid][1] = c1;
      }
      __syncthreads();
      if (t == 0) {
        out[i * 2 + 0] = red[0][0] + red[1][0] + red[2][0] + bo0;
        out[i * 2 + 1] = red[0][1] + red[1][1] + red[2][1] + bo1;
      }
    }
  }
}

extern "C" void kernel_launch(void* const* d_in, const int* in_sizes, int n_in,
                              void* d_out, int out_size, void* d_ws,
                              size_t ws_size, hipStream_t stream) {
  const float* des = (const float*)d_in[0];
  // d_in[1] = tweet : unused by the reference
  const float* num_prop = (const float*)d_in[2];
  const float* cat_prop = (const float*)d_in[3];
  const int* edge = (const int*)d_in[4];
  const float* W_des = (const float*)d_in[5];
  const float* b_des = (const float*)d_in[6];
  const float* W_num = (const float*)d_in[7];
  const float* b_num = (const float*)d_in[8];
  const float* W_cat = (const float*)d_in[9];
  const float* b_cat = (const float*)d_in[10];
  const float* W_in = (const float*)d_in[11];
  const float* b_in = (const float*)d_in[12];
  const float* W_g1 = (const float*)d_in[13];
  const float* b_g1 = (const float*)d_in[14];
  const float* W_g2 = (const float*)d_in[15];
  const float* b_g2 = (const float*)d_in[16];
  const float* W_o1 = (const float*)d_in[17];
  const float* b_o1 = (const float*)d_in[18];
  const float* W_o2 = (const float*)d_in[19];
  const float* b_o2 = (const float*)d_in[20];
  float* out = (float*)d_out;

  const int N = in_sizes[0] / DESK;  // 50000
  const int E = in_sizes[4] / 2;     // 800000
  const int* esrc = edge;
  const int* edst = edge + E;

  // workspace layout
  char* ws = (char*)d_ws;
  size_t off = 0;
  auto alloc = [&](size_t n) {
    off = (off + 255) & ~(size_t)255;
    size_t o = off;
    off += n;
    return o;
  };
  float* bufA = (float*)(ws + alloc((size_t)N * NFEAT * 4));  // x0 planes / y
  float* bufB = (float*)(ws + alloc((size_t)N * NFEAT * 4));  // x1 planes / w1
  int* deg = (int*)(ws + alloc((size_t)N * 4));
  int* offsets = (int*)(ws + alloc((size_t)(N + 1) * 4));
  int* cursor = (int*)(ws + alloc((size_t)N * 4));
  int* partial = (int*)(ws + alloc(1024 * 4));
  float* dinv = (float*)(ws + alloc((size_t)N * 4));
  float* svec = (float*)(ws + alloc((size_t)N * 4));
  int* csr_off = (int*)(ws + alloc((size_t)E * 4));
  float* csr_w = (float*)(ws + alloc((size_t)E * 4));
  float* T1 = (float*)(ws + alloc(384 * 384 * 4));
  float* Mmat = (float*)(ws + alloc(384 * 384 * 4));
  float* uvec = (float*)(ws + alloc(384 * 4));
  float* vvec = (float*)(ws + alloc(384 * 4));
  unsigned short* WdThi = (unsigned short*)(ws + alloc(768 * 128 * 2));
  unsigned short* WdTlo = (unsigned short*)(ws + alloc(768 * 128 * 2));
  unsigned short* WiThi = (unsigned short*)(ws + alloc(384 * 384 * 2));
  unsigned short* WiTlo = (unsigned short*)(ws + alloc(384 * 384 * 2));
  unsigned short* MmThi = (unsigned short*)(ws + alloc(384 * 384 * 2));
  unsigned short* MmTlo = (unsigned short*)(ws + alloc(384 * 384 * 2));
  (void)ws_size;
  (void)n_in;
  (void)out_size;

  unsigned short* x0hi = (unsigned short*)bufA;
  unsigned short* x0lo = x0hi + (size_t)N * NFEAT;
  unsigned short* x1hi = (unsigned short*)bufB;
  unsigned short* x1lo = x1hi + (size_t)N * NFEAT;
  _Float16* yb = (_Float16*)bufA;   // overwrites x0 planes after use
  _Float16* w1 = (_Float16*)bufB;   // overwrites x1 planes after use

  hipMemsetAsync(deg, 0, (size_t)N * 4, stream);

  // small precomputes: T1 = W_g2 @ W_o1 ; Mmat = W_g1 @ T1 ; u, v; B^T splits
  dim3 g6(6, 6);
  gemm384<<<g6, 256, 0, stream>>>(W_g2, W_o1, T1);
  gemm384<<<g6, 256, 0, stream>>>(W_g1, T1, Mmat);
  uv_kernel<<<2, 256, 0, stream>>>(T1, W_o1, b_g1, b_g2, b_o1, uvec, vvec);
  split_transpose_b<<<dim3(12, 24, 3), 256, 0, stream>>>(
      W_des, WdThi, WdTlo, W_in, WiThi, WiTlo, Mmat, MmThi, MmTlo);

  const int MT = (N + 127) / 128;  // 391
  // x0 cols 0..127 = leaky(des @ W_des + b_des) -> bf16 hi/lo planes
  mfma_gemm<1, 0><<<dim3(MT, 1), 256, 0, stream>>>(
      des, nullptr, nullptr, WdThi, WdTlo, nullptr, x0hi, x0lo, b_des, N, DESK,
      NFEAT);
  // x0 cols 128..383
  numcat_kernel<<<1024, 256, 0, stream>>>(num_prop, cat_prop, W_num, b_num,
                                          W_cat, b_cat, x0hi, x0lo, N);
  // x1 = leaky(x0 @ W_in + b_in) -> planes
  mfma_gemm<0, 0><<<dim3(MT, 3), 256, 0, stream>>>(
      nullptr, x0hi, x0lo, WiThi, WiTlo, nullptr, x1hi, x1lo, b_in, N, NFEAT,
      NFEAT);
  // y = x1 @ Mmat -> fp16 (overwrites x0 planes region)
  mfma_gemm<0, 1><<<dim3(MT, 3), 256, 0, stream>>>(
      nullptr, x1hi, x1lo, MmThi, MmTlo, yb, nullptr, nullptr, nullptr, N,
      NFEAT, NFEAT);

  // graph prep
  const int EB = (E + 255) / 256;
  count_kernel<<<EB, 256, 0, stream>>>(edst, deg, E);
  const int NB = (N + 511) / 512;
  scan_reduce<<<NB, 512, 0, stream>>>(deg, partial, N);
  scan_top<<<1, 64, 0, stream>>>(partial, NB);
  scan_down<<<NB, 512, 0, stream>>>(deg, partial, offsets, cursor, dinv, N, E);
  fill_kernel<<<EB, 256, 0, stream>>>(esrc, edst, cursor, csr_off, csr_w, dinv,
                                      E);

  // w1 = Ahat @ y (also s = Ahat @ 1) ; then fused final:
  // out = (leaky(Ahat @ w1 + s*u + v)) @ W_o2 + b_o2
  agg_kernel<1, 0><<<4096, 192, 0, stream>>>(
      yb, w1, offsets, csr_off, csr_w, dinv, svec, nullptr, nullptr, nullptr,
      nullptr, nullptr, nullptr, N);
  agg_kernel<0, 1><<<4096, 192, 0, stream>>>(
      w1, nullptr, offsets, csr_off, csr_w, dinv, nullptr, svec, uvec, vvec,
      W_o2, b_o2, out, N);
}